// Round 9
// baseline (2746.336 us; speedup 1.0000x reference)
//
#include <hip/hip_runtime.h>
#include <math.h>

// MambaBlock: B=8, T=2048, D_MODEL=1024, D_STATE=256.
// GEMMs: bf16 MFMA 128x128 tiles. Scan: 4 blocks x 2 batches each; two
// independent recurrence chains interleaved per CU so chain B's issue work
// fills chain A's LDS-roundtrip/MFMA-latency stalls. One barrier per step
// advances BOTH batches. Zero vmem instructions in the serial path.

enum { E_NONE = 0, E_BIASBF = 1, E_SIGBF = 2, E_ACC = 3, E_BIASRES = 4, E_CVTBF = 5 };

typedef __attribute__((ext_vector_type(8))) short bf16x8;
typedef __attribute__((ext_vector_type(4))) float f32x4;

static __device__ inline unsigned short f2bf(float f) {
    unsigned u = __builtin_bit_cast(unsigned, f);
    unsigned r = (u + 0x7fff + ((u >> 16) & 1)) >> 16;
    return (unsigned short)r;
}
static __device__ inline unsigned pack2(float a, float b) {
    return (unsigned)f2bf(a) | ((unsigned)f2bf(b) << 16);
}
static __device__ inline float bflo(unsigned u) {
    return __builtin_bit_cast(float, u << 16);
}
static __device__ inline float bfhi(unsigned u) {
    return __builtin_bit_cast(float, u & 0xffff0000u);
}
static __device__ inline float tanh_fast(float x) {
    float e = __builtin_amdgcn_exp2f(x * 2.8853900817779268f);
    float t = __builtin_amdgcn_rcpf(e + 1.0f);
    return fmaf(-2.0f, t, 1.0f);
}

// ---------------- prepass: f32 -> bf16 convert ----------------
__global__ __launch_bounds__(256) void cvt_bf(
    const float* __restrict__ in, unsigned short* __restrict__ out, int n8)
{
    int i = blockIdx.x * 256 + threadIdx.x;
    if (i >= n8) return;
    float4 a = ((const float4*)in)[i * 2];
    float4 b = ((const float4*)in)[i * 2 + 1];
    uint4 o;
    o.x = pack2(a.x, a.y); o.y = pack2(a.z, a.w);
    o.z = pack2(b.x, b.y); o.w = pack2(b.z, b.w);
    ((uint4*)out)[i] = o;
}

// ---------------- prepass: f32 [R,C] -> bf16 [C,R] transpose ----------------
__global__ __launch_bounds__(256) void transpose_bf(
    const float* __restrict__ in, unsigned short* __restrict__ out, int R, int C)
{
    __shared__ float tile[32][33];
    const int bx = blockIdx.x * 32, by = blockIdx.y * 32;
    const int tx = threadIdx.x & 31, ty = threadIdx.x >> 5;  // ty 0..7
#pragma unroll
    for (int i = 0; i < 32; i += 8)
        tile[ty + i][tx] = in[(size_t)(by + ty + i) * C + bx + tx];
    __syncthreads();
#pragma unroll
    for (int i = 0; i < 32; i += 8)
        out[(size_t)(bx + ty + i) * R + by + tx] = f2bf(tile[tx][ty + i]);
}

// ---------------- bf16 MFMA GEMM: C[M,N] = A[M,K] * B[N,K]^T ----------------
template <int EPI>
__global__ __launch_bounds__(256) void gemm_mfma(
    const unsigned short* __restrict__ Ag,  // [M,K] bf16
    const unsigned short* __restrict__ Bg,  // [N,K] bf16
    const float* __restrict__ bias, const float* __restrict__ res,
    void* Cg, int M, int N, int K)
{
    __shared__ __align__(16) unsigned char Lds[2][32768];  // [buf][A 16K | B 16K]
    const int tid = threadIdx.x;
    const int w = tid >> 6, l = tid & 63;
    const int r = l & 15, g = l >> 4;
    const int m0 = blockIdx.y * 128, n0 = blockIdx.x * 128;

    const unsigned char* agp[4];
    const unsigned char* bgp[4];
#pragma unroll
    for (int j = 0; j < 4; ++j) {
        const int c = w * 256 + j * 64 + l;
        const int row = c >> 3;
        const unsigned offp = ((unsigned)(c & 7) * 16u) ^ ((unsigned)(row & 7) * 16u);
        agp[j] = (const unsigned char*)Ag + ((size_t)(m0 + row) * K) * 2 + offp;
        bgp[j] = (const unsigned char*)Bg + ((size_t)(n0 + row) * K) * 2 + offp;
    }

#define STAGE(BUF)                                                            \
    {                                                                         \
      _Pragma("unroll")                                                       \
      for (int j = 0; j < 4; ++j) {                                           \
        __builtin_amdgcn_global_load_lds(                                     \
            (const __attribute__((address_space(1))) unsigned*)(agp[j]),      \
            (__attribute__((address_space(3))) unsigned*)&Lds[(BUF)][w * 4096 + j * 1024], \
            16, 0, 0);                                                        \
        __builtin_amdgcn_global_load_lds(                                     \
            (const __attribute__((address_space(1))) unsigned*)(bgp[j]),      \
            (__attribute__((address_space(3))) unsigned*)&Lds[(BUF)][16384 + w * 4096 + j * 1024], \
            16, 0, 0);                                                        \
        agp[j] += 128; bgp[j] += 128;                                         \
      }                                                                       \
    }

    f32x4 acc[2][8];
#pragma unroll
    for (int mt = 0; mt < 2; ++mt)
#pragma unroll
        for (int nt = 0; nt < 8; ++nt) acc[mt][nt] = (f32x4){0.f, 0.f, 0.f, 0.f};

    const int nk = K >> 6;
    STAGE(0)
    __syncthreads();
    for (int t = 0; t < nk; ++t) {
        const int buf = t & 1;
        if (t + 1 < nk) { STAGE(buf ^ 1) }
        bf16x8 af[2][2], bfr[8][2];
#pragma unroll
        for (int s = 0; s < 2; ++s) {
#pragma unroll
            for (int mt = 0; mt < 2; ++mt) {
                const int row = w * 32 + mt * 16 + r;
                af[mt][s] = *(const bf16x8*)&Lds[buf][row * 128 +
                    ((s * 64 + 16 * g) ^ (16 * (row & 7)))];
            }
#pragma unroll
            for (int nt = 0; nt < 8; ++nt) {
                const int row = nt * 16 + r;
                bfr[nt][s] = *(const bf16x8*)&Lds[buf][16384 + row * 128 +
                    ((s * 64 + 16 * g) ^ (16 * (row & 7)))];
            }
        }
#pragma unroll
        for (int s = 0; s < 2; ++s)
#pragma unroll
            for (int mt = 0; mt < 2; ++mt)
#pragma unroll
                for (int nt = 0; nt < 8; ++nt)
                    acc[mt][nt] = __builtin_amdgcn_mfma_f32_16x16x32_bf16(
                        af[mt][s], bfr[nt][s], acc[mt][nt], 0, 0, 0);
        __syncthreads();
    }
#undef STAGE

#pragma unroll
    for (int mt = 0; mt < 2; ++mt)
#pragma unroll
        for (int nt = 0; nt < 8; ++nt) {
            const int n = n0 + nt * 16 + r;
            float bv = 0.f;
            if (EPI == E_BIASBF || EPI == E_SIGBF || EPI == E_BIASRES) bv = bias[n];
#pragma unroll
            for (int q = 0; q < 4; ++q) {
                const int m = m0 + w * 32 + mt * 16 + g * 4 + q;
                const size_t idx = (size_t)m * N + n;
                float v = acc[mt][nt][q] + bv;
                if (EPI == E_SIGBF) v = 1.f / (1.f + expf(-v));
                if (EPI == E_ACC) v += ((const float*)Cg)[idx];
                if (EPI == E_BIASRES) v += res[idx];
                if (EPI == E_BIASBF || EPI == E_SIGBF || EPI == E_CVTBF)
                    ((unsigned short*)Cg)[idx] = f2bf(v);
                else
                    ((float*)Cg)[idx] = v;
            }
        }
}

// ---------------- dual-chain MFMA scan: 4 blocks, 2 batches each -----------
// Block p: batches 2p, 2p+1 — two independent chains interleaved in one
// instruction stream; one barrier per step advances both. Per chain per
// step: Y^T = A^T @ h (broadcast B-operand), select q=r&3, tanh, b16 write
// to the chain's 16-deep ring. u2 staged per 8-step chunk via
// global_load_lds; h dumped per chunk; counted vmcnt only.
__global__ __launch_bounds__(256, 1) void scan_mfma(
    const float* __restrict__ Amat, const unsigned short* __restrict__ u2bf,
    unsigned short* __restrict__ hbf)
{
    constexpr int T = 2048;
    constexpr int NCH = T / 8;  // 256 chunks
    __shared__ __align__(16) unsigned char LDSM[4 * 8192];
    unsigned char* HbA = LDSM;             // ring [16][512]
    unsigned char* HbB = LDSM + 8192;      // ring [16][512]
    unsigned char* UA  = LDSM + 16384;     // [2][8][512]
    unsigned char* UB  = LDSM + 24576;     // [2][8][512]

    const int tid = threadIdx.x;
    const int p = blockIdx.x;              // 0..3
    const int w = tid >> 6, l = tid & 63;
    const int r = l & 15, g = l >> 4;
    const int m0 = w * 64;
    const bool c1 = (r & 1) != 0, c2 = (r & 2) != 0;

    if (tid < 128) {                       // ring slot 0 = h_{-1} = 0
        ((unsigned*)HbA)[tid] = 0u;
        ((unsigned*)HbB)[tid] = 0u;
    }

    // A^T frags: af[mt][kt](lane r,g) = Amat[kt*32+g*8+j][m0+mt*16+r]
    bf16x8 af[4][8];
#pragma unroll
    for (int mt = 0; mt < 4; ++mt) {
        const int m = m0 + mt * 16 + r;
#pragma unroll
        for (int kt = 0; kt < 8; ++kt) {
            unsigned wd[4];
#pragma unroll
            for (int jw = 0; jw < 4; ++jw) {
                const int k = kt * 32 + g * 8 + jw * 2;
                wd[jw] = pack2(Amat[(size_t)k * 256 + m],
                               Amat[(size_t)(k + 1) * 256 + m]);
            }
            af[mt][kt] = __builtin_bit_cast(bf16x8, *(uint4*)wd);
        }
    }

    const unsigned char* uAsrc = (const unsigned char*)u2bf + (size_t)(2 * p) * T * 512;
    const unsigned char* uBsrc = (const unsigned char*)u2bf + (size_t)(2 * p + 1) * T * 512;
    unsigned char* hAdst = (unsigned char*)(hbf + (size_t)(2 * p) * T * 256);
    unsigned char* hBdst = (unsigned char*)(hbf + (size_t)(2 * p + 1) * T * 256);

    // prologue: stage chunks 0 and 1 for both batches
#pragma unroll
    for (int buf = 0; buf < 2; ++buf) {
        __builtin_amdgcn_global_load_lds(
            (const __attribute__((address_space(1))) unsigned*)(uAsrc + buf * 4096 + tid * 16),
            (__attribute__((address_space(3))) unsigned*)(UA + buf * 4096 + tid * 16), 16, 0, 0);
        __builtin_amdgcn_global_load_lds(
            (const __attribute__((address_space(1))) unsigned*)(uBsrc + buf * 4096 + tid * 16),
            (__attribute__((address_space(3))) unsigned*)(UB + buf * 4096 + tid * 16), 16, 0, 0);
    }
    asm volatile("s_waitcnt vmcnt(2) lgkmcnt(0)" ::: "memory");
    __builtin_amdgcn_sched_barrier(0);
    __builtin_amdgcn_s_barrier();
    __builtin_amdgcn_sched_barrier(0);

    // u-read byte offset within a step row (lane's selected state, q=r&3)
    unsigned uo[4];
#pragma unroll
    for (int mt = 0; mt < 4; ++mt)
        uo[mt] = (unsigned)((m0 + mt * 16 + g * 4 + (r & 3)) * 2);

#define CHAIN(HB, UC, PF0, PF1, US)                                           \
    {                                                                         \
      _Pragma("unroll")                                                       \
      for (int mt = 0; mt < 4; ++mt) {                                        \
        PF0[mt] = (f32x4){0.f, 0.f, 0.f, 0.f};                                \
        PF1[mt] = (f32x4){0.f, 0.f, 0.f, 0.f};                                \
      }                                                                       \
    }

#define SCAN_STEP(I)                                                          \
  {                                                                           \
    const unsigned ro = c15 + (I) * 512u;                                     \
    const unsigned bwb = ((I) == 7) ? (c15 ^ 4096u) : (c15 + ((I) + 1) * 512u);\
    bf16x8 hfA[8], hfB[8];                                                    \
    _Pragma("unroll")                                                         \
    for (int kt = 0; kt < 8; ++kt)                                            \
      hfA[kt] = *(const bf16x8*)(HbA + ro + (unsigned)(kt * 64 + g * 16));    \
    _Pragma("unroll")                                                         \
    for (int kt = 0; kt < 8; ++kt)                                            \
      hfB[kt] = *(const bf16x8*)(HbB + ro + (unsigned)(kt * 64 + g * 16));    \
    unsigned short usA[4], usB[4];                                            \
    _Pragma("unroll")                                                         \
    for (int mt = 0; mt < 4; ++mt) {                                          \
      usA[mt] = *(const unsigned short*)(UcA + (I) * 512u + uo[mt]);          \
      usB[mt] = *(const unsigned short*)(UcB + (I) * 512u + uo[mt]);          \
    }                                                                         \
    f32x4 pA0[4], pA1[4], pB0[4], pB1[4];                                     \
    CHAIN(HbA, UcA, pA0, pA1, usA)                                            \
    CHAIN(HbB, UcB, pB0, pB1, usB)                                            \
    _Pragma("unroll")                                                         \
    for (int kt = 0; kt < 4; ++kt) {                                          \
      _Pragma("unroll")                                                       \
      for (int mt = 0; mt < 4; ++mt) {                                        \
        pA0[mt] = __builtin_amdgcn_mfma_f32_16x16x32_bf16(af[mt][kt], hfA[kt],\
                                                          pA0[mt], 0, 0, 0);  \
        pA1[mt] = __builtin_amdgcn_mfma_f32_16x16x32_bf16(                    \
            af[mt][kt + 4], hfA[kt + 4], pA1[mt], 0, 0, 0);                   \
      }                                                                       \
    }                                                                         \
    _Pragma("unroll")                                                         \
    for (int kt = 0; kt < 4; ++kt) {                                          \
      _Pragma("unroll")                                                       \
      for (int mt = 0; mt < 4; ++mt) {                                        \
        pB0[mt] = __builtin_amdgcn_mfma_f32_16x16x32_bf16(af[mt][kt], hfB[kt],\
                                                          pB0[mt], 0, 0, 0);  \
        pB1[mt] = __builtin_amdgcn_mfma_f32_16x16x32_bf16(                    \
            af[mt][kt + 4], hfB[kt + 4], pB1[mt], 0, 0, 0);                   \
      }                                                                       \
    }                                                                         \
    _Pragma("unroll")                                                         \
    for (int mt = 0; mt < 4; ++mt) {                                          \
      float a0 = pA0[mt][0] + pA1[mt][0], a1 = pA0[mt][1] + pA1[mt][1];       \
      float a2 = pA0[mt][2] + pA1[mt][2], a3 = pA0[mt][3] + pA1[mt][3];       \
      float sa = c2 ? (c1 ? a3 : a2) : (c1 ? a1 : a0);                        \
      float ha = tanh_fast(sa + bflo((unsigned)usA[mt]));                     \
      float b0 = pB0[mt][0] + pB1[mt][0], b1 = pB0[mt][1] + pB1[mt][1];       \
      float b2 = pB0[mt][2] + pB1[mt][2], b3 = pB0[mt][3] + pB1[mt][3];       \
      float sb = c2 ? (c1 ? b3 : b2) : (c1 ? b1 : b0);                        \
      float hbv = tanh_fast(sb + bflo((unsigned)usB[mt]));                    \
      unsigned pka, pkb;                                                      \
      asm("v_cvt_pk_bf16_f32 %0, %1, %2" : "=v"(pka) : "v"(ha), "v"(ha));     \
      asm("v_cvt_pk_bf16_f32 %0, %1, %2" : "=v"(pkb) : "v"(hbv), "v"(hbv));   \
      if (r < 4) {                                                            \
        const unsigned wb = bwb + (unsigned)((m0 + mt * 16 + g * 4 + r) * 2); \
        *(unsigned short*)(HbA + wb) = (unsigned short)pka;                   \
        *(unsigned short*)(HbB + wb) = (unsigned short)pkb;                   \
      }                                                                       \
    }                                                                         \
    asm volatile("s_waitcnt lgkmcnt(0)" ::: "memory");                        \
    __builtin_amdgcn_sched_barrier(0);                                        \
    __builtin_amdgcn_s_barrier();                                             \
    __builtin_amdgcn_sched_barrier(0);                                        \
  }

    for (int chunk = 0; chunk < NCH; ++chunk) {
        const int t0 = chunk * 8;
        const unsigned c15 = (unsigned)(t0 & 15) * 512u;
        const unsigned char* UcA = UA + ((unsigned)(chunk & 1) << 12);
        const unsigned char* UcB = UB + ((unsigned)(chunk & 1) << 12);

        SCAN_STEP(0)
        SCAN_STEP(1)
        SCAN_STEP(2)
        SCAN_STEP(3)
        SCAN_STEP(4)
        SCAN_STEP(5)
        SCAN_STEP(6)
        SCAN_STEP(7)

        // dump this chunk's h for both batches (ring fully written)
        {
            const int i = tid >> 5;                 // 0..7 (step in chunk)
            const int byte = (tid & 31) * 16;
            const int slot = (t0 + 1 + i) & 15;
            uint4 da = *(const uint4*)(HbA + slot * 512 + byte);
            uint4 db = *(const uint4*)(HbB + slot * 512 + byte);
            *(uint4*)(hAdst + (size_t)(t0 + i) * 512 + byte) = da;
            *(uint4*)(hBdst + (size_t)(t0 + i) * 512 + byte) = db;
        }
        // stage chunk+2 into the U buffers this chunk just finished reading
        if (chunk + 2 < NCH) {
            const unsigned nb = (unsigned)(chunk & 1) << 12;
            __builtin_amdgcn_global_load_lds(
                (const __attribute__((address_space(1))) unsigned*)(
                    uAsrc + (size_t)(t0 + 16) * 512 + tid * 16),
                (__attribute__((address_space(3))) unsigned*)(UA + nb + tid * 16), 16, 0, 0);
            __builtin_amdgcn_global_load_lds(
                (const __attribute__((address_space(1))) unsigned*)(
                    uBsrc + (size_t)(t0 + 16) * 512 + tid * 16),
                (__attribute__((address_space(3))) unsigned*)(UB + nb + tid * 16), 16, 0, 0);
            asm volatile("s_waitcnt vmcnt(4)" ::: "memory");
        } else {
            asm volatile("s_waitcnt vmcnt(2)" ::: "memory");
        }
        __builtin_amdgcn_sched_barrier(0);
        __builtin_amdgcn_s_barrier();
        __builtin_amdgcn_sched_barrier(0);
    }
#undef SCAN_STEP
#undef CHAIN
}

// ---------------- elementwise gate: ys = g*big + (1-g)*x (bf16 out) --------
__global__ __launch_bounds__(256) void ewise(
    const unsigned short* __restrict__ g8, const float* __restrict__ big,
    const float* __restrict__ x, unsigned short* __restrict__ ys, int n8)
{
    int i = blockIdx.x * 256 + threadIdx.x;
    if (i >= n8) return;
    uint4 gv = ((const uint4*)g8)[i];
    float4 b0 = ((const float4*)big)[i * 2], b1 = ((const float4*)big)[i * 2 + 1];
    float4 x0 = ((const float4*)x)[i * 2], x1 = ((const float4*)x)[i * 2 + 1];
    float gg[8] = {bflo(gv.x), bfhi(gv.x), bflo(gv.y), bfhi(gv.y),
                   bflo(gv.z), bfhi(gv.z), bflo(gv.w), bfhi(gv.w)};
    float bb[8] = {b0.x, b0.y, b0.z, b0.w, b1.x, b1.y, b1.z, b1.w};
    float xx[8] = {x0.x, x0.y, x0.z, x0.w, x1.x, x1.y, x1.z, x1.w};
    float yy[8];
#pragma unroll
    for (int k = 0; k < 8; ++k) yy[k] = gg[k] * bb[k] + (1.f - gg[k]) * xx[k];
    uint4 o;
    o.x = pack2(yy[0], yy[1]); o.y = pack2(yy[2], yy[3]);
    o.z = pack2(yy[4], yy[5]); o.w = pack2(yy[6], yy[7]);
    ((uint4*)ys)[i] = o;
}

extern "C" void kernel_launch(void* const* d_in, const int* in_sizes, int n_in,
                              void* d_out, int out_size, void* d_ws, size_t ws_size,
                              hipStream_t stream)
{
    const float* x      = (const float*)d_in[0];
    const float* W_in   = (const float*)d_in[1];
    const float* b_in   = (const float*)d_in[2];
    const float* W_gate = (const float*)d_in[3];
    const float* b_gate = (const float*)d_in[4];
    const float* Amat   = (const float*)d_in[5];
    const float* Bm     = (const float*)d_in[6];
    const float* Cm     = (const float*)d_in[7];
    const float* Dm     = (const float*)d_in[8];
    const float* W_out  = (const float*)d_in[9];
    const float* b_out  = (const float*)d_in[10];

    const int T = 2048, DM = 1024, DS = 256;
    const int M = 8 * T;  // 16384
    const size_t MB = 1024 * 1024;
    char* ws = (char*)d_ws;

    unsigned short* xbf  = (unsigned short*)(ws);
    unsigned short* ysbf = xbf;  // reuse after gate GEMM
    unsigned short* u    = (unsigned short*)(ws + 32 * MB);
    unsigned short* u2   = (unsigned short*)(ws + 40 * MB);  // bf16 [16384,256]
    unsigned short* h    = (unsigned short*)(ws + 56 * MB);  // bf16 [16384,256]
    unsigned short* WinT = (unsigned short*)(ws + 64 * MB);
    unsigned short* BmT  = (unsigned short*)(ws + 64 * MB + 512 * 1024);
    unsigned short* WgT  = (unsigned short*)(ws + 65 * MB);
    unsigned short* WoT  = (unsigned short*)(ws + 67 * MB);
    unsigned short* Cbf  = (unsigned short*)(ws + 69 * MB);
    unsigned short* Dbf  = (unsigned short*)(ws + 69 * MB + 512 * 1024);
    float*          big  = (float*)(ws + 70 * MB);
    unsigned short* gbf  = (unsigned short*)(ws + 134 * MB);

    // prepass converts/transposes
    cvt_bf<<<M * DM / 8 / 256, 256, 0, stream>>>(x, xbf, M * DM / 8);
    transpose_bf<<<dim3(DS / 32, DM / 32), 256, 0, stream>>>(W_in, WinT, DM, DS);
    transpose_bf<<<dim3(DS / 32, DS / 32), 256, 0, stream>>>(Bm, BmT, DS, DS);
    transpose_bf<<<dim3(DM / 32, DM / 32), 256, 0, stream>>>(W_gate, WgT, DM, DM);
    transpose_bf<<<dim3(DM / 32, DM / 32), 256, 0, stream>>>(W_out, WoT, DM, DM);
    cvt_bf<<<DM * DS / 8 / 256, 256, 0, stream>>>(Cm, Cbf, DM * DS / 8);
    cvt_bf<<<DM * DS / 8 / 256, 256, 0, stream>>>(Dm, Dbf, DM * DS / 8);

    // u = bf16(x @ W_in + b_in)
    gemm_mfma<E_BIASBF><<<dim3(DS / 128, M / 128), 256, 0, stream>>>(
        xbf, WinT, b_in, nullptr, u, M, DS, DM);
    // big = u @ D^T
    gemm_mfma<E_NONE><<<dim3(DM / 128, M / 128), 256, 0, stream>>>(
        u, Dbf, nullptr, nullptr, big, M, DM, DS);
    // u2 = bf16(u @ Bm)
    gemm_mfma<E_CVTBF><<<dim3(DS / 128, M / 128), 256, 0, stream>>>(
        u, BmT, nullptr, nullptr, u2, M, DS, DS);
    // g = bf16(sigmoid(x @ W_gate + b_gate))
    gemm_mfma<E_SIGBF><<<dim3(DM / 128, M / 128), 256, 0, stream>>>(
        xbf, WgT, b_gate, nullptr, gbf, M, DM, DM);
    // h recurrence: 4 blocks x 2 interleaved batches
    scan_mfma<<<4, 256, 0, stream>>>(Amat, u2, h);
    // big += h @ C^T
    gemm_mfma<E_ACC><<<dim3(DM / 128, M / 128), 256, 0, stream>>>(
        h, Cbf, nullptr, nullptr, big, M, DM, DS);
    // ys = bf16(g*big + (1-g)*x)
    ewise<<<M * DM / 8 / 256, 256, 0, stream>>>(gbf, big, x, ysbf, M * DM / 8);
    // out = ys @ W_out + b_out + x
    gemm_mfma<E_BIASRES><<<dim3(DM / 128, M / 128), 256, 0, stream>>>(
        ysbf, WoT, b_out, x, (float*)d_out, M, DM, DM);
}

// Round 10
// 1539.566 us; speedup vs baseline: 1.7838x; 1.7838x over previous
//
#include <hip/hip_runtime.h>
#include <math.h>

// MambaBlock: B=8, T=2048, D_MODEL=1024, D_STATE=256.
// GEMMs: bf16 MFMA 128x128 tiles. Scan: ONE block, 8 waves (2/SIMD), all 8
// batches; matrix-pipe floor ~620 cy/step, tails hidden by co-resident wave.
// Zero vmem instructions in the serial path; chunked LDS staging/dump.

enum { E_NONE = 0, E_BIASBF = 1, E_SIGBF = 2, E_ACC = 3, E_BIASRES = 4, E_CVTBF = 5 };

typedef __attribute__((ext_vector_type(8))) short bf16x8;
typedef __attribute__((ext_vector_type(4))) float f32x4;

static __device__ inline unsigned short f2bf(float f) {
    unsigned u = __builtin_bit_cast(unsigned, f);
    unsigned r = (u + 0x7fff + ((u >> 16) & 1)) >> 16;
    return (unsigned short)r;
}
static __device__ inline unsigned pack2(float a, float b) {
    return (unsigned)f2bf(a) | ((unsigned)f2bf(b) << 16);
}
static __device__ inline float bflo(unsigned u) {
    return __builtin_bit_cast(float, u << 16);
}
static __device__ inline float bfhi(unsigned u) {
    return __builtin_bit_cast(float, u & 0xffff0000u);
}
static __device__ inline float tanh_fast(float x) {
    float e = __builtin_amdgcn_exp2f(x * 2.8853900817779268f);
    float t = __builtin_amdgcn_rcpf(e + 1.0f);
    return fmaf(-2.0f, t, 1.0f);
}

// ---------------- prepass: f32 -> bf16 convert ----------------
__global__ __launch_bounds__(256) void cvt_bf(
    const float* __restrict__ in, unsigned short* __restrict__ out, int n8)
{
    int i = blockIdx.x * 256 + threadIdx.x;
    if (i >= n8) return;
    float4 a = ((const float4*)in)[i * 2];
    float4 b = ((const float4*)in)[i * 2 + 1];
    uint4 o;
    o.x = pack2(a.x, a.y); o.y = pack2(a.z, a.w);
    o.z = pack2(b.x, b.y); o.w = pack2(b.z, b.w);
    ((uint4*)out)[i] = o;
}

// ---------------- prepass: f32 [R,C] -> bf16 [C,R] transpose ----------------
__global__ __launch_bounds__(256) void transpose_bf(
    const float* __restrict__ in, unsigned short* __restrict__ out, int R, int C)
{
    __shared__ float tile[32][33];
    const int bx = blockIdx.x * 32, by = blockIdx.y * 32;
    const int tx = threadIdx.x & 31, ty = threadIdx.x >> 5;  // ty 0..7
#pragma unroll
    for (int i = 0; i < 32; i += 8)
        tile[ty + i][tx] = in[(size_t)(by + ty + i) * C + bx + tx];
    __syncthreads();
#pragma unroll
    for (int i = 0; i < 32; i += 8)
        out[(size_t)(bx + ty + i) * R + by + tx] = f2bf(tile[tx][ty + i]);
}

// ---------------- bf16 MFMA GEMM: C[M,N] = A[M,K] * B[N,K]^T ----------------
template <int EPI>
__global__ __launch_bounds__(256) void gemm_mfma(
    const unsigned short* __restrict__ Ag,  // [M,K] bf16
    const unsigned short* __restrict__ Bg,  // [N,K] bf16
    const float* __restrict__ bias, const float* __restrict__ res,
    void* Cg, int M, int N, int K)
{
    __shared__ __align__(16) unsigned char Lds[2][32768];  // [buf][A 16K | B 16K]
    const int tid = threadIdx.x;
    const int w = tid >> 6, l = tid & 63;
    const int r = l & 15, g = l >> 4;
    const int m0 = blockIdx.y * 128, n0 = blockIdx.x * 128;

    const unsigned char* agp[4];
    const unsigned char* bgp[4];
#pragma unroll
    for (int j = 0; j < 4; ++j) {
        const int c = w * 256 + j * 64 + l;
        const int row = c >> 3;
        const unsigned offp = ((unsigned)(c & 7) * 16u) ^ ((unsigned)(row & 7) * 16u);
        agp[j] = (const unsigned char*)Ag + ((size_t)(m0 + row) * K) * 2 + offp;
        bgp[j] = (const unsigned char*)Bg + ((size_t)(n0 + row) * K) * 2 + offp;
    }

#define STAGE(BUF)                                                            \
    {                                                                         \
      _Pragma("unroll")                                                       \
      for (int j = 0; j < 4; ++j) {                                           \
        __builtin_amdgcn_global_load_lds(                                     \
            (const __attribute__((address_space(1))) unsigned*)(agp[j]),      \
            (__attribute__((address_space(3))) unsigned*)&Lds[(BUF)][w * 4096 + j * 1024], \
            16, 0, 0);                                                        \
        __builtin_amdgcn_global_load_lds(                                     \
            (const __attribute__((address_space(1))) unsigned*)(bgp[j]),      \
            (__attribute__((address_space(3))) unsigned*)&Lds[(BUF)][16384 + w * 4096 + j * 1024], \
            16, 0, 0);                                                        \
        agp[j] += 128; bgp[j] += 128;                                         \
      }                                                                       \
    }

    f32x4 acc[2][8];
#pragma unroll
    for (int mt = 0; mt < 2; ++mt)
#pragma unroll
        for (int nt = 0; nt < 8; ++nt) acc[mt][nt] = (f32x4){0.f, 0.f, 0.f, 0.f};

    const int nk = K >> 6;
    STAGE(0)
    __syncthreads();
    for (int t = 0; t < nk; ++t) {
        const int buf = t & 1;
        if (t + 1 < nk) { STAGE(buf ^ 1) }
        bf16x8 af[2][2], bfr[8][2];
#pragma unroll
        for (int s = 0; s < 2; ++s) {
#pragma unroll
            for (int mt = 0; mt < 2; ++mt) {
                const int row = w * 32 + mt * 16 + r;
                af[mt][s] = *(const bf16x8*)&Lds[buf][row * 128 +
                    ((s * 64 + 16 * g) ^ (16 * (row & 7)))];
            }
#pragma unroll
            for (int nt = 0; nt < 8; ++nt) {
                const int row = nt * 16 + r;
                bfr[nt][s] = *(const bf16x8*)&Lds[buf][16384 + row * 128 +
                    ((s * 64 + 16 * g) ^ (16 * (row & 7)))];
            }
        }
#pragma unroll
        for (int s = 0; s < 2; ++s)
#pragma unroll
            for (int mt = 0; mt < 2; ++mt)
#pragma unroll
                for (int nt = 0; nt < 8; ++nt)
                    acc[mt][nt] = __builtin_amdgcn_mfma_f32_16x16x32_bf16(
                        af[mt][s], bfr[nt][s], acc[mt][nt], 0, 0, 0);
        __syncthreads();
    }
#undef STAGE

#pragma unroll
    for (int mt = 0; mt < 2; ++mt)
#pragma unroll
        for (int nt = 0; nt < 8; ++nt) {
            const int n = n0 + nt * 16 + r;
            float bv = 0.f;
            if (EPI == E_BIASBF || EPI == E_SIGBF || EPI == E_BIASRES) bv = bias[n];
#pragma unroll
            for (int q = 0; q < 4; ++q) {
                const int m = m0 + w * 32 + mt * 16 + g * 4 + q;
                const size_t idx = (size_t)m * N + n;
                float v = acc[mt][nt][q] + bv;
                if (EPI == E_SIGBF) v = 1.f / (1.f + expf(-v));
                if (EPI == E_ACC) v += ((const float*)Cg)[idx];
                if (EPI == E_BIASRES) v += res[idx];
                if (EPI == E_BIASBF || EPI == E_SIGBF || EPI == E_CVTBF)
                    ((unsigned short*)Cg)[idx] = f2bf(v);
                else
                    ((float*)Cg)[idx] = v;
            }
        }
}

// ---------------- 8-wave MFMA scan: one block, all 8 batches ---------------
// Wave w owns output states [w*32, w*32+32) (2 m-tiles, 16 MFMAs/step).
// 2 waves/SIMD: co-wave's matrix time hides the tanh/LDS/barrier tail.
// h ring: 16 deep x 4KB, layout [kt][g*8+b][16B] (R7-verified, 0 conflicts).
// u2 bf16 staged per 8-step chunk (2x32KB, XOR-granule swizzle); chunk dump
// of h to global via coalesced ds_read_b128 + fire-and-forget stores; one
// counted vmcnt per chunk; zero vmem in the 8-step serial path.
// Split-tanh: lane r<8 handles q={0,1}, r>=8 handles q={2,3} of batch r&7.
__global__ __launch_bounds__(512, 2) void scan_mfma(
    const float* __restrict__ Amat, const unsigned short* __restrict__ u2bf,
    unsigned short* __restrict__ hbf)
{
    constexpr int T = 2048;
    constexpr int NCH = T / 8;  // 256 chunks
    __shared__ __align__(16) unsigned char LDSM[131072];
    unsigned char* Hb = LDSM;              // ring [16][4096]
    unsigned char* Ub = LDSM + 65536;      // [2 buf][8 steps][8 b][512 B]

    const int tid = threadIdx.x;
    const int w = tid >> 6, l = tid & 63;
    const int r = l & 15, g = l >> 4, r8 = r & 7;
    const bool hi = (r & 8) != 0;          // q-half this lane finishes
    const int m0 = w * 32;

    // zero ring slot 0 (h_{-1} = 0): 4096 B = 1024 u32
    ((unsigned*)Hb)[tid] = 0u;
    ((unsigned*)Hb)[tid + 512] = 0u;

    // A^T frags: af[mt][kt](lane r,g) = Amat[kt*32+g*8+j][m0+mt*16+r]
    bf16x8 af[2][8];
#pragma unroll
    for (int mt = 0; mt < 2; ++mt) {
        const int m = m0 + mt * 16 + r;
#pragma unroll
        for (int kt = 0; kt < 8; ++kt) {
            unsigned wd[4];
#pragma unroll
            for (int jw = 0; jw < 4; ++jw) {
                const int k = kt * 32 + g * 8 + jw * 2;
                wd[jw] = pack2(Amat[(size_t)k * 256 + m],
                               Amat[(size_t)(k + 1) * 256 + m]);
            }
            af[mt][kt] = __builtin_bit_cast(bf16x8, *(uint4*)wd);
        }
    }

    // per-lane constant offsets
    unsigned ubase[2], woff[2];
#pragma unroll
    for (int mt = 0; mt < 2; ++mt) {
        const int s0 = m0 + mt * 16 + g * 4;       // 4-state base of this frag row
        const int s = s0 + (hi ? 2 : 0);           // this lane's 2-state base
        ubase[mt] = (unsigned)(r8 * 512 + (((s >> 3) ^ r8) * 16) + (s & 7) * 2);
        woff[mt] = (unsigned)((((s0 >> 5) * 32 + ((s0 >> 3) & 3) * 8 + r8) * 16)
                              + ((s0 & 7) + (hi ? 2 : 0)) * 2);
    }
    const unsigned rbase = (unsigned)((g * 8 + r8) * 16);

    // staging piece decode (4 pieces/thread/chunk): dest d -> (i, b, src kg)
    int sg_i[4], sg_b[4], sg_kg[4];
#pragma unroll
    for (int j = 0; j < 4; ++j) {
        const int d = j * 512 + tid;
        sg_i[j] = d >> 8;
        sg_b[j] = (d >> 5) & 7;
        sg_kg[j] = (d & 31) ^ sg_b[j];
    }

    // prologue: stage chunks 0 and 1
#pragma unroll
    for (int c0 = 0; c0 < 2; ++c0)
#pragma unroll
        for (int j = 0; j < 4; ++j) {
            const size_t srcb = ((size_t)(sg_b[j] * T + c0 * 8 + sg_i[j]) * 512)
                              + (unsigned)(sg_kg[j] * 16);
            __builtin_amdgcn_global_load_lds(
                (const __attribute__((address_space(1))) unsigned*)(
                    (const unsigned char*)u2bf + srcb),
                (__attribute__((address_space(3))) unsigned*)(
                    Ub + c0 * 32768 + (j * 512 + tid) * 16), 16, 0, 0);
        }
    asm volatile("s_waitcnt vmcnt(0) lgkmcnt(0)" ::: "memory");
    __builtin_amdgcn_sched_barrier(0);
    __builtin_amdgcn_s_barrier();
    __builtin_amdgcn_sched_barrier(0);

#define SCAN_STEP(I)                                                          \
  {                                                                           \
    const unsigned sr = ((unsigned)(t0 + (I)) & 15u) * 4096u;                 \
    const unsigned sw = ((unsigned)(t0 + (I) + 1) & 15u) * 4096u;             \
    bf16x8 hf[8];                                                             \
    _Pragma("unroll")                                                         \
    for (int kt = 0; kt < 8; ++kt)                                            \
      hf[kt] = *(const bf16x8*)(Hb + sr + rbase + (unsigned)(kt * 512));      \
    unsigned uv[2];                                                           \
    _Pragma("unroll")                                                         \
    for (int mt = 0; mt < 2; ++mt)                                            \
      uv[mt] = *(const unsigned*)(Uc + (unsigned)(I) * 4096u + ubase[mt]);    \
    f32x4 p0[2], p1[2];                                                       \
    _Pragma("unroll")                                                         \
    for (int mt = 0; mt < 2; ++mt) {                                          \
      p0[mt] = (f32x4){0.f, 0.f, 0.f, 0.f};                                   \
      p1[mt] = (f32x4){0.f, 0.f, 0.f, 0.f};                                   \
    }                                                                         \
    _Pragma("unroll")                                                         \
    for (int kt = 0; kt < 4; ++kt) {                                          \
      _Pragma("unroll")                                                       \
      for (int mt = 0; mt < 2; ++mt) {                                        \
        p0[mt] = __builtin_amdgcn_mfma_f32_16x16x32_bf16(af[mt][kt], hf[kt],  \
                                                         p0[mt], 0, 0, 0);    \
        p1[mt] = __builtin_amdgcn_mfma_f32_16x16x32_bf16(                     \
            af[mt][kt + 4], hf[kt + 4], p1[mt], 0, 0, 0);                     \
      }                                                                       \
    }                                                                         \
    _Pragma("unroll")                                                         \
    for (int mt = 0; mt < 2; ++mt) {                                          \
      const float slo = hi ? (p0[mt][2] + p1[mt][2]) : (p0[mt][0] + p1[mt][0]);\
      const float shi = hi ? (p0[mt][3] + p1[mt][3]) : (p0[mt][1] + p1[mt][1]);\
      const float h0 = tanh_fast(slo + bflo(uv[mt]));                         \
      const float h1 = tanh_fast(shi + bfhi(uv[mt]));                         \
      unsigned pk;                                                            \
      asm("v_cvt_pk_bf16_f32 %0, %1, %2" : "=v"(pk) : "v"(h0), "v"(h1));      \
      *(unsigned*)(Hb + sw + woff[mt]) = pk;                                  \
    }                                                                         \
    asm volatile("s_waitcnt lgkmcnt(0)" ::: "memory");                        \
    __builtin_amdgcn_sched_barrier(0);                                        \
    __builtin_amdgcn_s_barrier();                                             \
    __builtin_amdgcn_sched_barrier(0);                                        \
  }

    for (int chunk = 0; chunk < NCH; ++chunk) {
        const int t0 = chunk * 8;
        const unsigned char* Uc = Ub + ((unsigned)(chunk & 1) << 15);

        SCAN_STEP(0)
        SCAN_STEP(1)
        SCAN_STEP(2)
        SCAN_STEP(3)
        SCAN_STEP(4)
        SCAN_STEP(5)
        SCAN_STEP(6)
        SCAN_STEP(7)

        // ---- chunk end: dump this chunk's h, stage chunk+2, counted vmcnt
        {
#pragma unroll
            for (int j = 0; j < 4; ++j) {
                const int p = j * 512 + tid;
                const int di = p >> 8, wp = p & 255;
                const int kt_ = wp >> 5, sl_ = wp & 31;
                const unsigned slot = (unsigned)((t0 + 1 + di) & 15) * 4096u;
                uint4 dat = *(const uint4*)(Hb + slot + (unsigned)wp * 16u);
                const size_t off = ((size_t)((sl_ & 7) * T + t0 + di) * 256 +
                                    kt_ * 32 + (sl_ >> 3) * 8);
                *(uint4*)(hbf + off) = dat;
            }
            if (chunk + 2 < NCH) {
                const unsigned nb = (unsigned)(chunk & 1) << 15;
#pragma unroll
                for (int j = 0; j < 4; ++j) {
                    const size_t srcb =
                        ((size_t)(sg_b[j] * T + t0 + 16 + sg_i[j]) * 512)
                        + (unsigned)(sg_kg[j] * 16);
                    __builtin_amdgcn_global_load_lds(
                        (const __attribute__((address_space(1))) unsigned*)(
                            (const unsigned char*)u2bf + srcb),
                        (__attribute__((address_space(3))) unsigned*)(
                            Ub + nb + (j * 512 + tid) * 16), 16, 0, 0);
                }
                asm volatile("s_waitcnt vmcnt(8) lgkmcnt(0)" ::: "memory");
            } else {
                asm volatile("s_waitcnt vmcnt(4) lgkmcnt(0)" ::: "memory");
            }
            __builtin_amdgcn_sched_barrier(0);
            __builtin_amdgcn_s_barrier();
            __builtin_amdgcn_sched_barrier(0);
        }
    }
#undef SCAN_STEP
}

// ---------------- elementwise gate: ys = g*big + (1-g)*x (bf16 out) --------
__global__ __launch_bounds__(256) void ewise(
    const unsigned short* __restrict__ g8, const float* __restrict__ big,
    const float* __restrict__ x, unsigned short* __restrict__ ys, int n8)
{
    int i = blockIdx.x * 256 + threadIdx.x;
    if (i >= n8) return;
    uint4 gv = ((const uint4*)g8)[i];
    float4 b0 = ((const float4*)big)[i * 2], b1 = ((const float4*)big)[i * 2 + 1];
    float4 x0 = ((const float4*)x)[i * 2], x1 = ((const float4*)x)[i * 2 + 1];
    float gg[8] = {bflo(gv.x), bfhi(gv.x), bflo(gv.y), bfhi(gv.y),
                   bflo(gv.z), bfhi(gv.z), bflo(gv.w), bfhi(gv.w)};
    float bb[8] = {b0.x, b0.y, b0.z, b0.w, b1.x, b1.y, b1.z, b1.w};
    float xx[8] = {x0.x, x0.y, x0.z, x0.w, x1.x, x1.y, x1.z, x1.w};
    float yy[8];
#pragma unroll
    for (int k = 0; k < 8; ++k) yy[k] = gg[k] * bb[k] + (1.f - gg[k]) * xx[k];
    uint4 o;
    o.x = pack2(yy[0], yy[1]); o.y = pack2(yy[2], yy[3]);
    o.z = pack2(yy[4], yy[5]); o.w = pack2(yy[6], yy[7]);
    ((uint4*)ys)[i] = o;
}

extern "C" void kernel_launch(void* const* d_in, const int* in_sizes, int n_in,
                              void* d_out, int out_size, void* d_ws, size_t ws_size,
                              hipStream_t stream)
{
    const float* x      = (const float*)d_in[0];
    const float* W_in   = (const float*)d_in[1];
    const float* b_in   = (const float*)d_in[2];
    const float* W_gate = (const float*)d_in[3];
    const float* b_gate = (const float*)d_in[4];
    const float* Amat   = (const float*)d_in[5];
    const float* Bm     = (const float*)d_in[6];
    const float* Cm     = (const float*)d_in[7];
    const float* Dm     = (const float*)d_in[8];
    const float* W_out  = (const float*)d_in[9];
    const float* b_out  = (const float*)d_in[10];

    const int T = 2048, DM = 1024, DS = 256;
    const int M = 8 * T;  // 16384
    const size_t MB = 1024 * 1024;
    char* ws = (char*)d_ws;

    unsigned short* xbf  = (unsigned short*)(ws);
    unsigned short* ysbf = xbf;  // reuse after gate GEMM
    unsigned short* u    = (unsigned short*)(ws + 32 * MB);
    unsigned short* u2   = (unsigned short*)(ws + 40 * MB);  // bf16 [16384,256]
    unsigned short* h    = (unsigned short*)(ws + 56 * MB);  // bf16 [16384,256]
    unsigned short* WinT = (unsigned short*)(ws + 64 * MB);
    unsigned short* BmT  = (unsigned short*)(ws + 64 * MB + 512 * 1024);
    unsigned short* WgT  = (unsigned short*)(ws + 65 * MB);
    unsigned short* WoT  = (unsigned short*)(ws + 67 * MB);
    unsigned short* Cbf  = (unsigned short*)(ws + 69 * MB);
    unsigned short* Dbf  = (unsigned short*)(ws + 69 * MB + 512 * 1024);
    float*          big  = (float*)(ws + 70 * MB);
    unsigned short* gbf  = (unsigned short*)(ws + 134 * MB);

    // prepass converts/transposes
    cvt_bf<<<M * DM / 8 / 256, 256, 0, stream>>>(x, xbf, M * DM / 8);
    transpose_bf<<<dim3(DS / 32, DM / 32), 256, 0, stream>>>(W_in, WinT, DM, DS);
    transpose_bf<<<dim3(DS / 32, DS / 32), 256, 0, stream>>>(Bm, BmT, DS, DS);
    transpose_bf<<<dim3(DM / 32, DM / 32), 256, 0, stream>>>(W_gate, WgT, DM, DM);
    transpose_bf<<<dim3(DM / 32, DM / 32), 256, 0, stream>>>(W_out, WoT, DM, DM);
    cvt_bf<<<DM * DS / 8 / 256, 256, 0, stream>>>(Cm, Cbf, DM * DS / 8);
    cvt_bf<<<DM * DS / 8 / 256, 256, 0, stream>>>(Dm, Dbf, DM * DS / 8);

    // u = bf16(x @ W_in + b_in)
    gemm_mfma<E_BIASBF><<<dim3(DS / 128, M / 128), 256, 0, stream>>>(
        xbf, WinT, b_in, nullptr, u, M, DS, DM);
    // big = u @ D^T
    gemm_mfma<E_NONE><<<dim3(DM / 128, M / 128), 256, 0, stream>>>(
        u, Dbf, nullptr, nullptr, big, M, DM, DS);
    // u2 = bf16(u @ Bm)
    gemm_mfma<E_CVTBF><<<dim3(DS / 128, M / 128), 256, 0, stream>>>(
        u, BmT, nullptr, nullptr, u2, M, DS, DS);
    // g = bf16(sigmoid(x @ W_gate + b_gate))
    gemm_mfma<E_SIGBF><<<dim3(DM / 128, M / 128), 256, 0, stream>>>(
        xbf, WgT, b_gate, nullptr, gbf, M, DM, DM);
    // h recurrence: one block, 8 waves, all batches
    scan_mfma<<<1, 512, 0, stream>>>(Amat, u2, h);
    // big += h @ C^T
    gemm_mfma<E_ACC><<<dim3(DM / 128, M / 128), 256, 0, stream>>>(
        h, Cbf, nullptr, nullptr, big, M, DM, DS);
    // ys = bf16(g*big + (1-g)*x)
    ewise<<<M * DM / 8 / 256, 256, 0, stream>>>(gbf, big, x, ysbf, M * DM / 8);
    // out = ys @ W_out + b_out + x
    gemm_mfma<E_BIASRES><<<dim3(DM / 128, M / 128), 256, 0, stream>>>(
        ysbf, WoT, b_out, x, (float*)d_out, M, DM, DM);
}

// Round 11
// 1444.720 us; speedup vs baseline: 1.9009x; 1.0656x over previous
//
#include <hip/hip_runtime.h>
#include <math.h>

// MambaBlock: B=8, T=2048, D_MODEL=1024, D_STATE=256.
// R11: scan (1 CU, 1275us) fused with all scan-independent work (gate GEMM,
// D GEMM, W_out transpose, C convert) as extra role-blocks of one kernel,
// so 255 otherwise-idle CUs do that work under the scan's shadow.
// ewise folded into the C-GEMM epilogue (E_GATE).

enum { E_NONE = 0, E_BIASBF = 1, E_SIGBF = 2, E_GATE = 3, E_BIASRES = 4, E_CVTBF = 5 };

typedef __attribute__((ext_vector_type(8))) short bf16x8;
typedef __attribute__((ext_vector_type(4))) float f32x4;

static __device__ inline unsigned short f2bf(float f) {
    unsigned u = __builtin_bit_cast(unsigned, f);
    unsigned r = (u + 0x7fff + ((u >> 16) & 1)) >> 16;
    return (unsigned short)r;
}
static __device__ inline unsigned pack2(float a, float b) {
    return (unsigned)f2bf(a) | ((unsigned)f2bf(b) << 16);
}
static __device__ inline float bflo(unsigned u) {
    return __builtin_bit_cast(float, u << 16);
}
static __device__ inline float bfhi(unsigned u) {
    return __builtin_bit_cast(float, u & 0xffff0000u);
}
static __device__ inline float tanh_fast(float x) {
    float e = __builtin_amdgcn_exp2f(x * 2.8853900817779268f);
    float t = __builtin_amdgcn_rcpf(e + 1.0f);
    return fmaf(-2.0f, t, 1.0f);
}

// ---------------- bf16 convert (device body + kernel) ----------------
static __device__ __forceinline__ void cvt_body(
    const float* __restrict__ in, unsigned short* __restrict__ out, int i, int n8)
{
    if (i >= n8) return;
    float4 a = ((const float4*)in)[i * 2];
    float4 b = ((const float4*)in)[i * 2 + 1];
    uint4 o;
    o.x = pack2(a.x, a.y); o.y = pack2(a.z, a.w);
    o.z = pack2(b.x, b.y); o.w = pack2(b.z, b.w);
    ((uint4*)out)[i] = o;
}

__global__ __launch_bounds__(256) void cvt_bf(
    const float* __restrict__ in, unsigned short* __restrict__ out, int n8)
{
    cvt_body(in, out, blockIdx.x * 256 + threadIdx.x, n8);
}

// ---------------- transpose f32 [R,C] -> bf16 [C,R] ----------------
static __device__ __forceinline__ void transpose_tile(
    bool act, unsigned char* LdsB, int bxi, int byi, int t2,
    const float* __restrict__ in, unsigned short* __restrict__ out, int R, int C)
{
    float* tile = (float*)LdsB;  // [32][33]
    const int bx = bxi * 32, by = byi * 32;
    const int tx = t2 & 31, ty = t2 >> 5;  // ty 0..7
    if (act) {
#pragma unroll
        for (int i = 0; i < 32; i += 8)
            tile[(ty + i) * 33 + tx] = in[(size_t)(by + ty + i) * C + bx + tx];
    }
    __syncthreads();
    if (act) {
#pragma unroll
        for (int i = 0; i < 32; i += 8)
            out[(size_t)(bx + ty + i) * R + by + tx] = f2bf(tile[tx * 33 + ty + i]);
    }
}

__global__ __launch_bounds__(256) void transpose_bf(
    const float* __restrict__ in, unsigned short* __restrict__ out, int R, int C)
{
    __shared__ __align__(16) unsigned char Lds[32 * 33 * 4];
    transpose_tile(true, Lds, blockIdx.x, blockIdx.y, threadIdx.x, in, out, R, C);
}

// ---------------- bf16 MFMA GEMM tile: C[M,N] = A[M,K] * B[N,K]^T ----------
// act: thread participates in work (barriers executed by ALL threads).
template <int EPI>
static __device__ __forceinline__ void gemm_tile(
    bool act, unsigned char* Lds, int bx, int by, int tid,
    const unsigned short* __restrict__ Ag,  // [M,K] bf16
    const unsigned short* __restrict__ Bg,  // [N,K] bf16
    const float* __restrict__ bias, const float* __restrict__ res,
    const float* __restrict__ acc_src, const unsigned short* __restrict__ g8,
    void* Cg, int M, int N, int K)
{
    const int w = (tid >> 6) & 3, l = tid & 63;
    const int r = l & 15, g = l >> 4;
    const int m0 = by * 128, n0 = bx * 128;

    const unsigned char* agp[4];
    const unsigned char* bgp[4];
#pragma unroll
    for (int j = 0; j < 4; ++j) {
        const int c = w * 256 + j * 64 + l;
        const int row = c >> 3;
        const unsigned offp = ((unsigned)(c & 7) * 16u) ^ ((unsigned)(row & 7) * 16u);
        agp[j] = (const unsigned char*)Ag + ((size_t)(m0 + row) * K) * 2 + offp;
        bgp[j] = (const unsigned char*)Bg + ((size_t)(n0 + row) * K) * 2 + offp;
    }

#define GSTAGE(BUF)                                                           \
    {                                                                         \
      _Pragma("unroll")                                                       \
      for (int j = 0; j < 4; ++j) {                                           \
        __builtin_amdgcn_global_load_lds(                                     \
            (const __attribute__((address_space(1))) unsigned*)(agp[j]),      \
            (__attribute__((address_space(3))) unsigned*)(Lds + (BUF) * 32768 + w * 4096 + j * 1024), \
            16, 0, 0);                                                        \
        __builtin_amdgcn_global_load_lds(                                     \
            (const __attribute__((address_space(1))) unsigned*)(bgp[j]),      \
            (__attribute__((address_space(3))) unsigned*)(Lds + (BUF) * 32768 + 16384 + w * 4096 + j * 1024), \
            16, 0, 0);                                                        \
        agp[j] += 128; bgp[j] += 128;                                         \
      }                                                                       \
    }

    f32x4 acc[2][8];
#pragma unroll
    for (int mt = 0; mt < 2; ++mt)
#pragma unroll
        for (int nt = 0; nt < 8; ++nt) acc[mt][nt] = (f32x4){0.f, 0.f, 0.f, 0.f};

    const int nk = K >> 6;
    if (act) GSTAGE(0)
    __syncthreads();
    for (int t = 0; t < nk; ++t) {
        const int buf = t & 1;
        if (act) {
            if (t + 1 < nk) GSTAGE(buf ^ 1)
            bf16x8 af[2][2], bfr[8][2];
#pragma unroll
            for (int s = 0; s < 2; ++s) {
#pragma unroll
                for (int mt = 0; mt < 2; ++mt) {
                    const int row = w * 32 + mt * 16 + r;
                    af[mt][s] = *(const bf16x8*)(Lds + buf * 32768 + row * 128 +
                        ((s * 64 + 16 * g) ^ (16 * (row & 7))));
                }
#pragma unroll
                for (int nt = 0; nt < 8; ++nt) {
                    const int row = nt * 16 + r;
                    bfr[nt][s] = *(const bf16x8*)(Lds + buf * 32768 + 16384 + row * 128 +
                        ((s * 64 + 16 * g) ^ (16 * (row & 7))));
                }
            }
#pragma unroll
            for (int s = 0; s < 2; ++s)
#pragma unroll
                for (int mt = 0; mt < 2; ++mt)
#pragma unroll
                    for (int nt = 0; nt < 8; ++nt)
                        acc[mt][nt] = __builtin_amdgcn_mfma_f32_16x16x32_bf16(
                            af[mt][s], bfr[nt][s], acc[mt][nt], 0, 0, 0);
        }
        __syncthreads();
    }
#undef GSTAGE

    if (act) {
#pragma unroll
        for (int mt = 0; mt < 2; ++mt)
#pragma unroll
            for (int nt = 0; nt < 8; ++nt) {
                const int n = n0 + nt * 16 + r;
                float bv = 0.f;
                if (EPI == E_BIASBF || EPI == E_SIGBF || EPI == E_BIASRES) bv = bias[n];
#pragma unroll
                for (int q = 0; q < 4; ++q) {
                    const int m = m0 + w * 32 + mt * 16 + g * 4 + q;
                    const size_t idx = (size_t)m * N + n;
                    float v = acc[mt][nt][q] + bv;
                    if (EPI == E_SIGBF) v = 1.f / (1.f + expf(-v));
                    if (EPI == E_BIASRES) v += res[idx];
                    if (EPI == E_GATE) {
                        v += acc_src[idx];
                        const float gg = bflo((unsigned)g8[idx]);
                        v = gg * v + (1.f - gg) * res[idx];
                    }
                    if (EPI == E_BIASBF || EPI == E_SIGBF || EPI == E_CVTBF ||
                        EPI == E_GATE)
                        ((unsigned short*)Cg)[idx] = f2bf(v);
                    else
                        ((float*)Cg)[idx] = v;
                }
            }
    }
}

template <int EPI>
__global__ __launch_bounds__(256) void gemm_mfma(
    const unsigned short* __restrict__ Ag, const unsigned short* __restrict__ Bg,
    const float* __restrict__ bias, const float* __restrict__ res,
    const float* __restrict__ acc_src, const unsigned short* __restrict__ g8,
    void* Cg, int M, int N, int K)
{
    __shared__ __align__(16) unsigned char Lds[65536];
    gemm_tile<EPI>(true, Lds, blockIdx.x, blockIdx.y, threadIdx.x,
                   Ag, Bg, bias, res, acc_src, g8, Cg, M, N, K);
}

// ---------------- 8-wave MFMA scan body (R10-verified, unchanged) ----------
static __device__ __forceinline__ void scan_body(
    unsigned char* LDSM, int tid,
    const float* __restrict__ Amat, const unsigned short* __restrict__ u2bf,
    unsigned short* __restrict__ hbf)
{
    constexpr int T = 2048;
    constexpr int NCH = T / 8;  // 256 chunks
    unsigned char* Hb = LDSM;              // ring [16][4096]
    unsigned char* Ub = LDSM + 65536;      // [2 buf][8 steps][8 b][512 B]

    const int w = tid >> 6, l = tid & 63;
    const int r = l & 15, g = l >> 4, r8 = r & 7;
    const bool hi = (r & 8) != 0;
    const int m0 = w * 32;

    ((unsigned*)Hb)[tid] = 0u;
    ((unsigned*)Hb)[tid + 512] = 0u;

    bf16x8 af[2][8];
#pragma unroll
    for (int mt = 0; mt < 2; ++mt) {
        const int m = m0 + mt * 16 + r;
#pragma unroll
        for (int kt = 0; kt < 8; ++kt) {
            unsigned wd[4];
#pragma unroll
            for (int jw = 0; jw < 4; ++jw) {
                const int k = kt * 32 + g * 8 + jw * 2;
                wd[jw] = pack2(Amat[(size_t)k * 256 + m],
                               Amat[(size_t)(k + 1) * 256 + m]);
            }
            af[mt][kt] = __builtin_bit_cast(bf16x8, *(uint4*)wd);
        }
    }

    unsigned ubase[2], woff[2];
#pragma unroll
    for (int mt = 0; mt < 2; ++mt) {
        const int s0 = m0 + mt * 16 + g * 4;
        const int s = s0 + (hi ? 2 : 0);
        ubase[mt] = (unsigned)(r8 * 512 + (((s >> 3) ^ r8) * 16) + (s & 7) * 2);
        woff[mt] = (unsigned)((((s0 >> 5) * 32 + ((s0 >> 3) & 3) * 8 + r8) * 16)
                              + ((s0 & 7) + (hi ? 2 : 0)) * 2);
    }
    const unsigned rbase = (unsigned)((g * 8 + r8) * 16);

    int sg_i[4], sg_b[4], sg_kg[4];
#pragma unroll
    for (int j = 0; j < 4; ++j) {
        const int d = j * 512 + tid;
        sg_i[j] = d >> 8;
        sg_b[j] = (d >> 5) & 7;
        sg_kg[j] = (d & 31) ^ sg_b[j];
    }

#pragma unroll
    for (int c0 = 0; c0 < 2; ++c0)
#pragma unroll
        for (int j = 0; j < 4; ++j) {
            const size_t srcb = ((size_t)(sg_b[j] * T + c0 * 8 + sg_i[j]) * 512)
                              + (unsigned)(sg_kg[j] * 16);
            __builtin_amdgcn_global_load_lds(
                (const __attribute__((address_space(1))) unsigned*)(
                    (const unsigned char*)u2bf + srcb),
                (__attribute__((address_space(3))) unsigned*)(
                    Ub + c0 * 32768 + (j * 512 + tid) * 16), 16, 0, 0);
        }
    asm volatile("s_waitcnt vmcnt(0) lgkmcnt(0)" ::: "memory");
    __builtin_amdgcn_sched_barrier(0);
    __builtin_amdgcn_s_barrier();
    __builtin_amdgcn_sched_barrier(0);

#define SCAN_STEP(I)                                                          \
  {                                                                           \
    const unsigned sr = ((unsigned)(t0 + (I)) & 15u) * 4096u;                 \
    const unsigned sw = ((unsigned)(t0 + (I) + 1) & 15u) * 4096u;             \
    bf16x8 hf[8];                                                             \
    _Pragma("unroll")                                                         \
    for (int kt = 0; kt < 8; ++kt)                                            \
      hf[kt] = *(const bf16x8*)(Hb + sr + rbase + (unsigned)(kt * 512));      \
    unsigned uv[2];                                                           \
    _Pragma("unroll")                                                         \
    for (int mt = 0; mt < 2; ++mt)                                            \
      uv[mt] = *(const unsigned*)(Uc + (unsigned)(I) * 4096u + ubase[mt]);    \
    f32x4 p0[2], p1[2];                                                       \
    _Pragma("unroll")                                                         \
    for (int mt = 0; mt < 2; ++mt) {                                          \
      p0[mt] = (f32x4){0.f, 0.f, 0.f, 0.f};                                   \
      p1[mt] = (f32x4){0.f, 0.f, 0.f, 0.f};                                   \
    }                                                                         \
    _Pragma("unroll")                                                         \
    for (int kt = 0; kt < 4; ++kt) {                                          \
      _Pragma("unroll")                                                       \
      for (int mt = 0; mt < 2; ++mt) {                                        \
        p0[mt] = __builtin_amdgcn_mfma_f32_16x16x32_bf16(af[mt][kt], hf[kt],  \
                                                         p0[mt], 0, 0, 0);    \
        p1[mt] = __builtin_amdgcn_mfma_f32_16x16x32_bf16(                     \
            af[mt][kt + 4], hf[kt + 4], p1[mt], 0, 0, 0);                     \
      }                                                                       \
    }                                                                         \
    _Pragma("unroll")                                                         \
    for (int mt = 0; mt < 2; ++mt) {                                          \
      const float slo = hi ? (p0[mt][2] + p1[mt][2]) : (p0[mt][0] + p1[mt][0]);\
      const float shi = hi ? (p0[mt][3] + p1[mt][3]) : (p0[mt][1] + p1[mt][1]);\
      const float h0 = tanh_fast(slo + bflo(uv[mt]));                         \
      const float h1 = tanh_fast(shi + bfhi(uv[mt]));                         \
      unsigned pk;                                                            \
      asm("v_cvt_pk_bf16_f32 %0, %1, %2" : "=v"(pk) : "v"(h0), "v"(h1));      \
      *(unsigned*)(Hb + sw + woff[mt]) = pk;                                  \
    }                                                                         \
    asm volatile("s_waitcnt lgkmcnt(0)" ::: "memory");                        \
    __builtin_amdgcn_sched_barrier(0);                                        \
    __builtin_amdgcn_s_barrier();                                             \
    __builtin_amdgcn_sched_barrier(0);                                        \
  }

    for (int chunk = 0; chunk < NCH; ++chunk) {
        const int t0 = chunk * 8;
        const unsigned char* Uc = Ub + ((unsigned)(chunk & 1) << 15);

        SCAN_STEP(0)
        SCAN_STEP(1)
        SCAN_STEP(2)
        SCAN_STEP(3)
        SCAN_STEP(4)
        SCAN_STEP(5)
        SCAN_STEP(6)
        SCAN_STEP(7)

        {
#pragma unroll
            for (int j = 0; j < 4; ++j) {
                const int p = j * 512 + tid;
                const int di = p >> 8, wp = p & 255;
                const int kt_ = wp >> 5, sl_ = wp & 31;
                const unsigned slot = (unsigned)((t0 + 1 + di) & 15) * 4096u;
                uint4 dat = *(const uint4*)(Hb + slot + (unsigned)wp * 16u);
                const size_t off = ((size_t)((sl_ & 7) * T + t0 + di) * 256 +
                                    kt_ * 32 + (sl_ >> 3) * 8);
                *(uint4*)(hbf + off) = dat;
            }
            if (chunk + 2 < NCH) {
                const unsigned nb = (unsigned)(chunk & 1) << 15;
#pragma unroll
                for (int j = 0; j < 4; ++j) {
                    const size_t srcb =
                        ((size_t)(sg_b[j] * T + t0 + 16 + sg_i[j]) * 512)
                        + (unsigned)(sg_kg[j] * 16);
                    __builtin_amdgcn_global_load_lds(
                        (const __attribute__((address_space(1))) unsigned*)(
                            (const unsigned char*)u2bf + srcb),
                        (__attribute__((address_space(3))) unsigned*)(
                            Ub + nb + (j * 512 + tid) * 16), 16, 0, 0);
                }
                asm volatile("s_waitcnt vmcnt(8) lgkmcnt(0)" ::: "memory");
            } else {
                asm volatile("s_waitcnt vmcnt(4) lgkmcnt(0)" ::: "memory");
            }
            __builtin_amdgcn_sched_barrier(0);
            __builtin_amdgcn_s_barrier();
            __builtin_amdgcn_sched_barrier(0);
        }
    }
#undef SCAN_STEP
}

// ---------------- fused kernel: scan + gate GEMM + D GEMM + prep -----------
// block 0: scan (512 thr). blocks 1..1024: gate GEMM. 1025..2048: D GEMM.
// 2049..3072: W_out transpose. 3073..3200: C convert. Non-scan roles use
// threads 0..255 (act guard); all 512 threads execute barriers.
__global__ __launch_bounds__(512, 1) void fused_scan(
    const float* __restrict__ Amat, const unsigned short* __restrict__ u2bf,
    unsigned short* __restrict__ hbf,
    const unsigned short* __restrict__ xbf, const unsigned short* __restrict__ WgT,
    const float* __restrict__ b_gate, unsigned short* __restrict__ gbf,
    const unsigned short* __restrict__ u, const unsigned short* __restrict__ Dbf,
    float* __restrict__ big,
    const float* __restrict__ W_out, unsigned short* __restrict__ WoT,
    const float* __restrict__ Cm, unsigned short* __restrict__ Cbf,
    int M, int DM, int DS)
{
    __shared__ __align__(16) unsigned char LDSM[131072];
    const int tid = threadIdx.x;
    const unsigned bid = blockIdx.x;

    if (bid == 0) {
        scan_body(LDSM, tid, Amat, u2bf, hbf);
        return;
    }
    const bool act = tid < 256;
    const int t2 = tid & 255;
    if (bid <= 1024) {
        const int t = bid - 1;
        gemm_tile<E_SIGBF>(act, LDSM, t & 7, t >> 3, t2, xbf, WgT, b_gate,
                           nullptr, nullptr, nullptr, gbf, M, DM, DM);
    } else if (bid <= 2048) {
        const int t = bid - 1025;
        gemm_tile<E_NONE>(act, LDSM, t & 7, t >> 3, t2, u, Dbf, nullptr,
                          nullptr, nullptr, nullptr, big, M, DM, DS);
    } else if (bid <= 3072) {
        const int t = bid - 2049;
        transpose_tile(act, LDSM, t & 31, t >> 5, t2, W_out, WoT, DM, DM);
    } else {
        const int t = bid - 3073;
        if (act) cvt_body(Cm, Cbf, t * 256 + t2, DM * DS / 8);
    }
}

extern "C" void kernel_launch(void* const* d_in, const int* in_sizes, int n_in,
                              void* d_out, int out_size, void* d_ws, size_t ws_size,
                              hipStream_t stream)
{
    const float* x      = (const float*)d_in[0];
    const float* W_in   = (const float*)d_in[1];
    const float* b_in   = (const float*)d_in[2];
    const float* W_gate = (const float*)d_in[3];
    const float* b_gate = (const float*)d_in[4];
    const float* Amat   = (const float*)d_in[5];
    const float* Bm     = (const float*)d_in[6];
    const float* Cm     = (const float*)d_in[7];
    const float* Dm     = (const float*)d_in[8];
    const float* W_out  = (const float*)d_in[9];
    const float* b_out  = (const float*)d_in[10];

    const int T = 2048, DM = 1024, DS = 256;
    const int M = 8 * T;  // 16384
    const size_t MB = 1024 * 1024;
    char* ws = (char*)d_ws;

    unsigned short* xbf  = (unsigned short*)(ws);
    unsigned short* ysbf = xbf;  // reuse after gate GEMM consumed xbf
    unsigned short* u    = (unsigned short*)(ws + 32 * MB);
    unsigned short* u2   = (unsigned short*)(ws + 40 * MB);  // bf16 [16384,256]
    unsigned short* h    = (unsigned short*)(ws + 56 * MB);  // bf16 [16384,256]
    unsigned short* WinT = (unsigned short*)(ws + 64 * MB);
    unsigned short* BmT  = (unsigned short*)(ws + 64 * MB + 512 * 1024);
    unsigned short* WgT  = (unsigned short*)(ws + 65 * MB);
    unsigned short* WoT  = (unsigned short*)(ws + 67 * MB);
    unsigned short* Cbf  = (unsigned short*)(ws + 69 * MB);
    unsigned short* Dbf  = (unsigned short*)(ws + 69 * MB + 512 * 1024);
    float*          big  = (float*)(ws + 70 * MB);
    unsigned short* gbf  = (unsigned short*)(ws + 134 * MB);

    // prepass: only what the pre-scan GEMMs and fused kernel's GEMMs need
    cvt_bf<<<M * DM / 8 / 256, 256, 0, stream>>>(x, xbf, M * DM / 8);
    transpose_bf<<<dim3(DS / 32, DM / 32), 256, 0, stream>>>(W_in, WinT, DM, DS);
    transpose_bf<<<dim3(DS / 32, DS / 32), 256, 0, stream>>>(Bm, BmT, DS, DS);
    transpose_bf<<<dim3(DM / 32, DM / 32), 256, 0, stream>>>(W_gate, WgT, DM, DM);
    cvt_bf<<<DM * DS / 8 / 256, 256, 0, stream>>>(Dm, Dbf, DM * DS / 8);

    // u = bf16(x @ W_in + b_in)
    gemm_mfma<E_BIASBF><<<dim3(DS / 128, M / 128), 256, 0, stream>>>(
        xbf, WinT, b_in, nullptr, nullptr, nullptr, u, M, DS, DM);
    // u2 = bf16(u @ Bm)
    gemm_mfma<E_CVTBF><<<dim3(DS / 128, M / 128), 256, 0, stream>>>(
        u, BmT, nullptr, nullptr, nullptr, nullptr, u2, M, DS, DS);

    // fused: scan (block 0) + gate GEMM + D GEMM + WoT transpose + C cvt
    fused_scan<<<3201, 512, 0, stream>>>(
        Amat, u2, h, xbf, WgT, b_gate, gbf, u, Dbf, big, W_out, WoT, Cm, Cbf,
        M, DM, DS);

    // ysbf = bf16( g * (h @ C^T + big) + (1-g) * x )   [ewise fused in epi]
    gemm_mfma<E_GATE><<<dim3(DM / 128, M / 128), 256, 0, stream>>>(
        h, Cbf, nullptr, x, big, gbf, ysbf, M, DM, DS);
    // out = ys @ W_out + b_out + x
    gemm_mfma<E_BIASRES><<<dim3(DM / 128, M / 128), 256, 0, stream>>>(
        ysbf, WoT, b_out, x, nullptr, nullptr, (float*)d_out, M, DM, DM);
}